// Round 6
// baseline (2223.221 us; speedup 1.0000x reference)
//
#include <hip/hip_runtime.h>
#include <hip/hip_bf16.h>
#include <math.h>

// Shapes (fixed): B=2 N=4 G=2 Ck=64 Cv=512 H=W=64 HW=4096 L=256 TOPL=64 Cin=1152 BN=8 BNG=16

typedef __attribute__((ext_vector_type(8))) short bf16x8;
typedef __attribute__((ext_vector_type(4))) float f32x4;
typedef __attribute__((ext_vector_type(16))) float f32x16;

static __device__ __forceinline__ short f2b(float f){
  __hip_bfloat16 h = __float2bfloat16(f);
  short s; __builtin_memcpy(&s, &h, 2); return s;
}
static __device__ __forceinline__ unsigned pack2(float lo, float hi){
  return (unsigned)(unsigned short)f2b(lo) | ((unsigned)(unsigned short)f2b(hi) << 16);
}

static __device__ __forceinline__ float wred_max(float v){
  #pragma unroll
  for (int off = 32; off > 0; off >>= 1) v = fmaxf(v, __shfl_xor(v, off));
  return v;
}
static __device__ __forceinline__ float wred_sum(float v){
  #pragma unroll
  for (int off = 32; off > 0; off >>= 1) v += __shfl_xor(v, off);
  return v;
}

// async global->LDS DMA, 16B per lane (dest = uniform base + lane*16)
static __device__ __forceinline__ void gload_lds16(const short* g, short* l){
  __builtin_amdgcn_global_load_lds((const __attribute__((address_space(1))) unsigned int*)(g),
                                   (__attribute__((address_space(3))) unsigned int*)(l),
                                   16, 0, 0);
}

#define FMA16(X0,X1,X2,X3,KV) \
  acc[0]+=X0.x*KV; acc[1]+=X0.y*KV; acc[2]+=X0.z*KV; acc[3]+=X0.w*KV; \
  acc[4]+=X1.x*KV; acc[5]+=X1.y*KV; acc[6]+=X1.z*KV; acc[7]+=X1.w*KV; \
  acc[8]+=X2.x*KV; acc[9]+=X2.y*KV; acc[10]+=X2.z*KV; acc[11]+=X2.w*KV; \
  acc[12]+=X3.x*KV; acc[13]+=X3.y*KV; acc[14]+=X3.z*KV; acc[15]+=X3.w*KV;

// ---------------- prep kernels ----------------

__global__ void k_prep_x(const float* __restrict__ qk, float* __restrict__ xT, float* __restrict__ xTn){
  int idx = blockIdx.x*256 + threadIdx.x;   // 8192 = B*HW
  int b = idx >> 12, hw = idx & 4095;
  float v[64]; float ss = 0.f;
  #pragma unroll
  for (int k=0;k<64;k++){ v[k] = qk[((size_t)b*64 + k)*4096 + hw]; ss += v[k]*v[k]; }
  float inv = 1.f/(sqrtf(ss) + 1e-6f);
  #pragma unroll
  for (int k=0;k<64;k++){ xT[(size_t)idx*64 + k] = v[k]; xTn[(size_t)idx*64 + k] = v[k]*inv; }
}

__global__ void k_init_w_kn(const float* __restrict__ masks, const float* __restrict__ kappa0,
                            float* __restrict__ wts, float* __restrict__ kn){
  int t = blockIdx.x*256 + threadIdx.x;   // 65536
  if (t < 16*4096) wts[t] = masks[t];
  if (t < 16*256){
    int bng = t >> 8, l = t & 255;
    float ss = 0.f;
    #pragma unroll 4
    for (int k=0;k<64;k++){ float v = kappa0[((size_t)bng*64 + k)*256 + l]; ss += v*v; }
    float inv = 1.f/(sqrtf(ss) + 1e-6f);
    #pragma unroll 4
    for (int k=0;k<64;k++) kn[((size_t)bng*64 + k)*256 + l] = kappa0[((size_t)bng*64 + k)*256 + l]*inv;
  }
}

// Interleaved weight layout: Wt2[((tile*2 + conv)*9216) + (r*2 + kh)*512 + cvl*8 + j]
//   tile = cvb*72 + cb; fragment-contiguous for 32x32x16 A-operand.
// v6: coalesced rewrite — block = (conv, cvb, cb); stage 64x144 f32 slab via
// float4 loads into padded LDS (pad 145 kills the stride-144 bank aliasing),
// emit coalesced bf16x8 stores. Replaces the old stride-36B gather (2 launches).
__global__ __launch_bounds__(256) void k_prep_wt2b(const float* __restrict__ Wf, const float* __restrict__ Wa,
                                                   short* __restrict__ Wt2){
  __shared__ float wsl[64][145];
  int blk = blockIdx.x;                 // 1152 = 576 tiles * 2 conv
  int conv = blk & 1;
  int tile = blk >> 1;                  // cvb*72 + cb
  int cb = tile % 72;
  int cvb = tile / 72;
  const float* Wsrc = conv ? Wa : Wf;
  int t = threadIdx.x;
  int cvl = t >> 2, part = t & 3;
  const float* src = Wsrc + ((size_t)(cvb*64 + cvl)*1152 + cb*16)*9;
  #pragma unroll
  for (int i = 0; i < 9; i++){
    float4 v = *(const float4*)(src + part*4 + i*16);
    wsl[cvl][part*4 + i*16 + 0] = v.x;
    wsl[cvl][part*4 + i*16 + 1] = v.y;
    wsl[cvl][part*4 + i*16 + 2] = v.z;
    wsl[cvl][part*4 + i*16 + 3] = v.w;
  }
  __syncthreads();
  short* obase = Wt2 + ((size_t)tile*2 + conv)*9216;
  #pragma unroll
  for (int i = 0; i < 5; i++){
    int item = t + i*256;               // [0,1152): (r*2+kh)*64 + cvl2
    if (item < 1152){
      int rk = item >> 6;
      int r = rk >> 1, kh = rk & 1;
      int c2 = item & 63;
      bf16x8 v;
      #pragma unroll
      for (int j = 0; j < 8; j++)
        v[j] = f2b(wsl[c2][(kh*8 + j)*9 + r]);
      *(bf16x8*)(obase + (size_t)item*8) = v;
    }
  }
}

// fin32 pair layout: fin32[bn*576*4096 + p*4096 + hw] = bf16 channels (2p, 2p+1)
// pairs [256,512) = qv broadcast over n
__global__ void k_qv_fin(const float* __restrict__ qv, unsigned* __restrict__ fin32){
  int t = blockIdx.x*256 + threadIdx.x;   // 8 * 2^20 threads
  int bn = t >> 20;
  int rem = t & 1048575;
  int p = rem >> 12;
  int hw = rem & 4095;
  int b = bn >> 2;
  float lo = qv[((size_t)b*512 + 2*p)*4096 + hw];
  float hi = qv[((size_t)b*512 + 2*p + 1)*4096 + hw];
  fin32[(size_t)bn*2359296 + (size_t)(256 + p)*4096 + hw] = pack2(lo, hi);
}

// ---------------- EM loop kernels ----------------

__global__ __launch_bounds__(256) void k_zz(const float* __restrict__ xT, const float* __restrict__ kn,
                                            const float* __restrict__ wts, float* __restrict__ zzb){
  int blk = blockIdx.x;                 // 4096 = 16 bng * 256 tiles
  int bng = blk >> 8;
  int hw0 = (blk & 255) * 16;
  int b = bng >> 3;
  int t = threadIdx.x;
  int lane = t & 63, wid = t >> 6;
  __shared__ float xs[64][16];
  __shared__ float redm[4], reds[4];
  {
    int k = t & 63, pq = t >> 6;
    #pragma unroll
    for (int p = pq; p < 16; p += 4)
      xs[k][p] = xT[((size_t)b*4096 + hw0 + p)*64 + k];
  }
  float acc[16];
  #pragma unroll
  for (int p=0;p<16;p++) acc[p] = 0.f;
  __syncthreads();
  const float* knp = kn + (size_t)bng*16384 + t;
  #pragma unroll 2
  for (int k=0;k<64;k++){
    float knv = knp[k*256];
    float4 x0 = *(const float4*)&xs[k][0];
    float4 x1 = *(const float4*)&xs[k][4];
    float4 x2 = *(const float4*)&xs[k][8];
    float4 x3 = *(const float4*)&xs[k][12];
    FMA16(x0,x1,x2,x3,knv)
  }
  #pragma unroll
  for (int p=0;p<16;p++){
    float v = acc[p];
    float m = wred_max(v);
    if (lane==0) redm[wid] = m;
    __syncthreads();
    m = fmaxf(fmaxf(redm[0],redm[1]), fmaxf(redm[2],redm[3]));
    float e = __expf((v - m) * 20.0f);
    float s = wred_sum(e);
    if (lane==0) reds[wid] = s;
    __syncthreads();
    s = reds[0]+reds[1]+reds[2]+reds[3];
    float wgt = wts[bng*4096 + hw0 + p];
    zzb[((size_t)bng*4096 + hw0 + p)*256 + t] = e/s*wgt;
  }
}

// v6: zz chunk staged in LDS once (cooperative, each element read once from
// global) instead of 4x redundant per-kq reads — zzb traffic /4 per launch.
__global__ __launch_bounds__(1024) void k_part(const float* __restrict__ qk, const float* __restrict__ zzb,
                                               float* __restrict__ kpart, float* __restrict__ zpart){
  int bng = blockIdx.x >> 4, ch = blockIdx.x & 15;   // 256 blocks
  int b = bng >> 3;
  int t = threadIdx.x; int l = t & 255; int kq = t >> 8;
  __shared__ float xs[64][80];
  __shared__ float zlds[16][256];
  float acc[16];
  #pragma unroll
  for (int j=0;j<16;j++) acc[j]=0.f;
  float zs = 0.f;
  for (int sc=0; sc<4; sc++){
    int hwb = ch*256 + sc*64;
    __syncthreads();
    {
      int hw_l = t & 63, kk = t >> 6;
      #pragma unroll
      for (int k = kk; k < 64; k += 16)
        xs[hw_l][k] = qk[((size_t)b*64 + k)*4096 + hwb + hw_l];
    }
    for (int chunk=0; chunk<4; chunk++){
      #pragma unroll
      for (int i=0;i<4;i++){
        int e = t + i*1024;
        int hh = e >> 8, l2 = e & 255;
        zlds[hh][l2] = zzb[((size_t)bng*4096 + hwb + chunk*16 + hh)*256 + l2];
      }
      __syncthreads();
      #pragma unroll 2
      for (int hh=0; hh<16; hh++){
        int hw_l = chunk*16 + hh;
        float zv = zlds[hh][l];
        zs += zv;
        const float* xp = &xs[hw_l][kq*16];
        float4 x0 = *(const float4*)(xp);
        float4 x1 = *(const float4*)(xp+4);
        float4 x2 = *(const float4*)(xp+8);
        float4 x3 = *(const float4*)(xp+12);
        FMA16(x0,x1,x2,x3,zv)
      }
      __syncthreads();
    }
  }
  #pragma unroll
  for (int j=0;j<16;j++)
    kpart[(((size_t)bng*16 + ch)*64 + kq*16 + j)*256 + l] = acc[j];
  if (kq == 0) zpart[((size_t)bng*16 + ch)*256 + l] = zs;
}

__global__ __launch_bounds__(1024) void k_fin(const float* __restrict__ kpart, const float* __restrict__ zpart,
                                              const float* __restrict__ kappa0, const float* __restrict__ zita0,
                                              float* __restrict__ kn, float* __restrict__ zita){
  int bng = blockIdx.x; int t = threadIdx.x; int l = t & 255; int kq = t >> 8;
  float z0 = zita0[bng*256 + l];
  float zs = z0;
  #pragma unroll
  for (int ch=0; ch<16; ch++) zs += zpart[((size_t)bng*16 + ch)*256 + l];
  if (kq==0) zita[bng*256 + l] = zs;
  float inv = 1.f/zs;
  float kap[16]; float ss = 0.f;
  #pragma unroll
  for (int j=0;j<16;j++){
    int k = kq*16 + j;
    float a = z0 * kappa0[((size_t)bng*64 + k)*256 + l];
    #pragma unroll
    for (int ch=0; ch<16; ch++) a += kpart[(((size_t)bng*16 + ch)*64 + k)*256 + l];
    float kv = a*inv; kap[j] = kv; ss += kv*kv;
  }
  __shared__ float ssr[4][256];
  ssr[kq][l] = ss;
  __syncthreads();
  float tot = ssr[0][l]+ssr[1][l]+ssr[2][l]+ssr[3][l];
  float ninv = 1.f/(sqrtf(tot) + 1e-6f);
  #pragma unroll
  for (int j=0;j<16;j++) kn[((size_t)bng*64 + kq*16 + j)*256 + l] = kap[j]*ninv;
}

__global__ __launch_bounds__(512) void k_sww(const float* __restrict__ xTn, const float* __restrict__ kn,
                                             const float* __restrict__ masks, float* __restrict__ wts){
  int blk = blockIdx.x;                 // 2048 = 8 bn * 256 tiles
  int bnI = blk >> 8;
  int hw0 = (blk & 255)*16;
  int b = bnI >> 2;
  int t = threadIdx.x;
  int lane = t & 63, wid = t >> 6;
  int g = t >> 8; int l = t & 255;
  int bng = bnI*2 + g;
  __shared__ float xs[64][16];
  __shared__ float redm[8], reds[8];
  {
    int k = t & 63, pq = t >> 6;
    #pragma unroll
    for (int p = pq; p < 16; p += 8)
      xs[k][p] = xTn[((size_t)b*4096 + hw0 + p)*64 + k];
  }
  float knr[64];
  const float* knp = kn + (size_t)bng*16384 + l;
  #pragma unroll
  for (int k=0;k<64;k++) knr[k] = knp[k*256];
  float acc[16];
  #pragma unroll
  for (int p=0;p<16;p++) acc[p]=0.f;
  __syncthreads();
  #pragma unroll 2
  for (int k=0;k<64;k++){
    float knv = knr[k];
    float4 x0 = *(const float4*)&xs[k][0];
    float4 x1 = *(const float4*)&xs[k][4];
    float4 x2 = *(const float4*)&xs[k][8];
    float4 x3 = *(const float4*)&xs[k][12];
    FMA16(x0,x1,x2,x3,knv)
  }
  #pragma unroll
  for (int p=0;p<16;p++){
    float v = acc[p];
    float m = wred_max(v);
    if (lane==0) redm[wid] = m;
    __syncthreads();
    m = fmaxf(fmaxf(fmaxf(redm[0],redm[1]),fmaxf(redm[2],redm[3])),
              fmaxf(fmaxf(redm[4],redm[5]),fmaxf(redm[6],redm[7])));
    float e = __expf((v - m) * 20.0f);
    float s = wred_sum(e);
    if (lane==0) reds[wid] = s;
    __syncthreads();
    float s0 = reds[0]+reds[1]+reds[2]+reds[3];
    float s1 = reds[4]+reds[5]+reds[6]+reds[7];
    if (lane==0 && (wid==0 || wid==4)){
      float sg = g ? s1 : s0;
      wts[bng*4096 + hw0 + p] = masks[bng*4096 + hw0 + p]*(1.f - sg/(s0+s1));
    }
  }
}

__global__ __launch_bounds__(512) void k_aff(const float* __restrict__ xTn, const float* __restrict__ kn,
                                             float* __restrict__ paff){
  int blk = blockIdx.x;                 // 2048
  int bnI = blk >> 8;
  int hw0 = (blk & 255)*16;
  int b = bnI >> 2;
  int t = threadIdx.x;
  int lane = t & 63, wid = t >> 6;
  int g = t >> 8; int l = t & 255;
  int bng = bnI*2 + g;
  __shared__ float xs[64][16];
  __shared__ float redm[8], reds[8];
  {
    int k = t & 63, pq = t >> 6;
    #pragma unroll
    for (int p = pq; p < 16; p += 8)
      xs[k][p] = xTn[((size_t)b*4096 + hw0 + p)*64 + k];
  }
  float knr[64];
  const float* knp = kn + (size_t)bng*16384 + l;
  #pragma unroll
  for (int k=0;k<64;k++) knr[k] = knp[k*256];
  float acc[16];
  #pragma unroll
  for (int p=0;p<16;p++) acc[p]=0.f;
  __syncthreads();
  #pragma unroll 2
  for (int k=0;k<64;k++){
    float knv = knr[k];
    float4 x0 = *(const float4*)&xs[k][0];
    float4 x1 = *(const float4*)&xs[k][4];
    float4 x2 = *(const float4*)&xs[k][8];
    float4 x3 = *(const float4*)&xs[k][12];
    FMA16(x0,x1,x2,x3,knv)
  }
  #pragma unroll
  for (int p=0;p<16;p++){
    float v = acc[p];
    float m = wred_max(v);
    if (lane==0) redm[wid] = m;
    __syncthreads();
    m = fmaxf(fmaxf(fmaxf(redm[0],redm[1]),fmaxf(redm[2],redm[3])),
              fmaxf(fmaxf(redm[4],redm[5]),fmaxf(redm[6],redm[7])));
    float e = __expf((v - m) * 20.0f);
    float s = wred_sum(e);
    if (lane==0) reds[wid] = s;
    __syncthreads();
    float tot = reds[0]+reds[1]+reds[2]+reds[3]+reds[4]+reds[5]+reds[6]+reds[7];
    paff[((size_t)bnI*4096 + hw0 + p)*512 + t] = e/tot;
  }
}

// ---------------- top-k / S channels ----------------

static __device__ __forceinline__ float topk_cum(float va, float vb, float vc, float vd, int lane){
  float run = 0.f, cme = 0.f;
  #pragma unroll 2
  for (int tt=0; tt<64; tt++){
    float m = fmaxf(fmaxf(va,vb), fmaxf(vc,vd));
    float wm = wred_max(m);
    run += wm;
    if (lane == tt) cme = run;
    unsigned long long ball = __ballot(m == wm);
    int wl = __ffsll(ball) - 1;
    if (lane == wl){
      if (va == wm) va = -1.f;
      else if (vb == wm) vb = -1.f;
      else if (vc == wm) vc = -1.f;
      else vd = -1.f;
    }
  }
  return cme;
}

__global__ __launch_bounds__(256) void k_topk(const float* __restrict__ paff, unsigned* __restrict__ fin32){
  int wid = threadIdx.x >> 6, lane = threadIdx.x & 63;
  int px = blockIdx.x*4 + wid;           // 32768 pixels
  int bn = px >> 12, hw = px & 4095;
  const float* row = paff + (size_t)px*512;
  float4 a0 = *(const float4*)(row + lane*4);
  float4 a1 = *(const float4*)(row + 256 + lane*4);
  float c0 = topk_cum(a0.x,a0.y,a0.z,a0.w, lane);
  float c1 = topk_cum(a1.x,a1.y,a1.z,a1.w, lane);
  float sf = c0/(c0+c1);
  float sf2 = __shfl_down(sf, 1);
  if (!(lane & 1)){
    size_t base = (size_t)bn*2359296;
    fin32[base + (size_t)(512 + (lane>>1))*4096 + hw] = pack2(sf, sf2);
    fin32[base + (size_t)(544 + (lane>>1))*4096 + hw] = pack2(1.f - sf, 1.f - sf2);
  }
}

// ---------------- MFMA GEMMs ----------------

// nu: C[cv][l] = qv_mem[bn] (Cv x HW) . zz[bng] (HW x L); epilogue -> mv2 bf16
// v6: lb merged 4->2 (l-tile 128, wave tile 32x64, acc 2x4) — halves the 8x
// redundant qvm A-panel traffic (1.07GB -> 536MB) and doubles MFMA density
// per staging barrier. Grid 256.
__global__ __launch_bounds__(256) void k_nu(const float* __restrict__ qvm, const float* __restrict__ zzb,
                                            const float* __restrict__ nu0, const float* __restrict__ zita0,
                                            const float* __restrict__ zita, short* __restrict__ mv2){
  constexpr int AP = 40;
  __shared__ short lA[64*AP];
  __shared__ short lB[128*AP];
  int blk = blockIdx.x;                  // 256 = 16 bng * 8 cvb * 2 lb
  int bng = blk >> 4, cvb = (blk >> 1) & 7, lb = blk & 1;
  int bn = bng >> 1, g = bng & 1;
  int t = threadIdx.x, lane = t & 63, w = t >> 6;
  int wm = w >> 1, wn = w & 1;
  int quad = lane >> 4, fr = lane & 15;
  f32x4 acc[2][4] = {};
  const float* Ab = qvm + ((size_t)bn*512 + cvb*64)*4096;
  const float* Bb = zzb + (size_t)bng*4096*256 + lb*128;
  int arow = t >> 2, acg = (t & 3)*8;
  int bhw = t & 31, blg = (t >> 5)*8;
  for (int k0 = 0; k0 < 4096; k0 += 32){
    __syncthreads();
    {
      const float* s = Ab + (size_t)arow*4096 + k0 + acg;
      float4 f0 = *(const float4*)s, f1 = *(const float4*)(s+4);
      bf16x8 v;
      v[0]=f2b(f0.x); v[1]=f2b(f0.y); v[2]=f2b(f0.z); v[3]=f2b(f0.w);
      v[4]=f2b(f1.x); v[5]=f2b(f1.y); v[6]=f2b(f1.z); v[7]=f2b(f1.w);
      *(bf16x8*)&lA[arow*AP + acg] = v;
    }
    #pragma unroll
    for (int h = 0; h < 2; h++){
      int l0 = h*64 + blg;
      const float* s = Bb + (size_t)(k0 + bhw)*256 + l0;
      float4 f0 = *(const float4*)s, f1 = *(const float4*)(s+4);
      lB[(l0+0)*AP + bhw] = f2b(f0.x);
      lB[(l0+1)*AP + bhw] = f2b(f0.y);
      lB[(l0+2)*AP + bhw] = f2b(f0.z);
      lB[(l0+3)*AP + bhw] = f2b(f0.w);
      lB[(l0+4)*AP + bhw] = f2b(f1.x);
      lB[(l0+5)*AP + bhw] = f2b(f1.y);
      lB[(l0+6)*AP + bhw] = f2b(f1.z);
      lB[(l0+7)*AP + bhw] = f2b(f1.w);
    }
    __syncthreads();
    int koff = quad*8;
    bf16x8 a0 = *(const bf16x8*)&lA[(wm*32 +  0 + fr)*AP + koff];
    bf16x8 a1 = *(const bf16x8*)&lA[(wm*32 + 16 + fr)*AP + koff];
    #pragma unroll
    for (int nf=0; nf<4; nf++){
      bf16x8 bv = *(const bf16x8*)&lB[(wn*64 + nf*16 + fr)*AP + koff];
      acc[0][nf] = __builtin_amdgcn_mfma_f32_16x16x32_bf16(a0,bv,acc[0][nf],0,0,0);
      acc[1][nf] = __builtin_amdgcn_mfma_f32_16x16x32_bf16(a1,bv,acc[1][nf],0,0,0);
    }
  }
  #pragma unroll
  for (int mf=0; mf<2; mf++)
  #pragma unroll
  for (int nf=0; nf<4; nf++)
  #pragma unroll
  for (int r=0;r<4;r++){
    int cv = cvb*64 + wm*32 + mf*16 + quad*4 + r;
    int l  = lb*128 + wn*64 + nf*16 + fr;
    float c = acc[mf][nf][r];
    float z0 = zita0[bng*256 + l];
    float nv = (z0 * nu0[((size_t)bng*512 + cv)*256 + l] + c) / zita[bng*256 + l];
    mv2[((size_t)bn*512 + cv)*512 + g*256 + l] = f2b(nv);
  }
}

// mem_out: C[cv][hw] = mv2[bn] (Cv x 2L) . p_aff[bn] (2L x HW) -> fin32 pairs [0,256)
__global__ __launch_bounds__(256) void k_mem(const short* __restrict__ mv2, const float* __restrict__ paff,
                                             unsigned* __restrict__ fin32){
  constexpr int BP = 40;
  __shared__ short lB[256*BP];
  int blk = blockIdx.x;                  // 1024 = 8 bn * 8 cvb * 16 hwb
  int bn = blk >> 7, cvb = (blk >> 4) & 7, hwb = blk & 15;
  int t = threadIdx.x, lane = t & 63, w = t >> 6;
  int quad = lane >> 4, fr = lane & 15;
  f32x4 acc[4][4] = {};
  const short* Ab = mv2 + ((size_t)bn*512 + cvb*64)*512;
  const float* Bb = paff + ((size_t)bn*4096 + hwb*256)*512;
  for (int k0=0; k0<512; k0+=32){
    __syncthreads();
    {
      const float* s = Bb + (size_t)t*512 + k0;
      #pragma unroll
      for (int q=0;q<4;q++){
        float4 f0 = *(const float4*)(s + q*8);
        float4 f1 = *(const float4*)(s + q*8 + 4);
        bf16x8 v;
        v[0]=f2b(f0.x); v[1]=f2b(f0.y); v[2]=f2b(f0.z); v[3]=f2b(f0.w);
        v[4]=f2b(f1.x); v[5]=f2b(f1.y); v[6]=f2b(f1.z); v[7]=f2b(f1.w);
        *(bf16x8*)&lB[t*BP + q*8] = v;
      }
    }
    __syncthreads();
    int koff = quad*8;
    bf16x8 af[4];
    #pragma unroll
    for (int mf=0; mf<4; mf++)
      af[mf] = *(const bf16x8*)(Ab + (size_t)(mf*16 + fr)*512 + k0 + koff);
    #pragma unroll
    for (int nf=0; nf<4; nf++){
      bf16x8 bv = *(const bf16x8*)&lB[(w*64 + nf*16 + fr)*BP + koff];
      #pragma unroll
      for (int mf=0; mf<4; mf++)
        acc[mf][nf] = __builtin_amdgcn_mfma_f32_16x16x32_bf16(af[mf], bv, acc[mf][nf],0,0,0);
    }
  }
  #pragma unroll
  for (int mf=0;mf<4;mf++)
  #pragma unroll
  for (int nf=0;nf<4;nf++){
    int hw = hwb*256 + w*64 + nf*16 + fr;
    int p0 = cvb*32 + mf*8 + quad*2;     // pair index of (cv0,cv1)
    unsigned lo = pack2(acc[mf][nf][0], acc[mf][nf][1]);
    unsigned hi = pack2(acc[mf][nf][2], acc[mf][nf][3]);
    fin32[(size_t)bn*2359296 + (size_t)p0*4096 + hw] = lo;
    fin32[(size_t)bn*2359296 + (size_t)(p0+1)*4096 + hw] = hi;
  }
}

// ---- shared conv body macros (v3 structure: conflict-free staging, LDS-DMA weights) ----
// qv-fold: channels 256-511 of fin are qv broadcast over n -> their conv
// contribution U[b] is computed ONCE per b by k_convu (cb 32..63) and added in
// k_conv's epilogue. k_conv runs only the 40 n-dependent cb chunks. 39% FLOP cut.
// U layout: U[(h*2 + conv)*2 + b][cv][y][x]  (h = K-half of the qv range)

#define CONV_STAGE_DECL \
  unsigned stg[3][4];
#define CONV_LOAD_STG(CB) { \
    _Pragma("unroll") \
    for (int i = 0; i < 3; i++){ \
      int tk = wv*3 + i; \
      int skh = (tk >= 6) ? 1 : 0; \
      int srow = tk - skh*6; \
      int gy = y0 - 1 + srow; \
      bool ok = (gy >= 0 && gy < 64); \
      _Pragma("unroll") \
      for (int pj = 0; pj < 4; pj++) \
        stg[i][pj] = ok ? finB[(size_t)((CB)*8 + skh*4 + pj)*4096 + gy*64 + lane] : 0u; \
    } }
#define CONV_WRITE_STG { \
    _Pragma("unroll") \
    for (int i = 0; i < 3; i++){ \
      int tk = wv*3 + i; \
      int skh = (tk >= 6) ? 1 : 0; \
      int srow = tk - skh*6; \
      uint4 v; v.x = stg[i][0]; v.y = stg[i][1]; v.z = stg[i][2]; v.w = stg[i][3]; \
      *(uint4*)&lFu[((skh*6 + srow)*66 + lane + 1)*4] = v; \
    } }
#define CONV_DMA_W(CB) { \
    const short* src = Wslice + (size_t)(CB)*18432 + lane*8; \
    _Pragma("unroll") \
    for (int i = 0; i < 9; i++){ \
      int idx = wv*9 + i; \
      gload_lds16(src + idx*512, &wbuf[idx*512]); \
    } }
#define CONV_COMPUTE { \
    __builtin_amdgcn_s_setprio(1); \
    _Pragma("unroll 3") \
    for (int r9 = 0; r9 < 9; r9++){ \
      int dy = r9/3, dx = r9 - dy*3; \
      bf16x8 f0 = *(const bf16x8*)(wbuf + r9*1024 + kh*512 + ln*8); \
      bf16x8 f1 = *(const bf16x8*)(wbuf + r9*1024 + kh*512 + ln*8 + 256); \
      bf16x8 a0 = *(const bf16x8*)(wbuf + 9216 + r9*1024 + kh*512 + ln*8); \
      bf16x8 a1 = *(const bf16x8*)(wbuf + 9216 + r9*1024 + kh*512 + ln*8 + 256); \
      int row = wv + dy; \
      _Pragma("unroll") \
      for (int xh = 0; xh < 2; xh++){ \
        bf16x8 bv = *(const bf16x8*)((const short*)lFu + (((kh*6 + row)*66 + xh*32 + ln + dx)*8)); \
        accF[0][xh] = __builtin_amdgcn_mfma_f32_32x32x16_bf16(f0, bv, accF[0][xh],0,0,0); \
        accF[1][xh] = __builtin_amdgcn_mfma_f32_32x32x16_bf16(f1, bv, accF[1][xh],0,0,0); \
        accA[0][xh] = __builtin_amdgcn_mfma_f32_32x32x16_bf16(a0, bv, accA[0][xh],0,0,0); \
        accA[1][xh] = __builtin_amdgcn_mfma_f32_32x32x16_bf16(a1, bv, accA[1][xh],0,0,0); \
      } \
    } \
    __builtin_amdgcn_s_setprio(0); }
#define CONV_HALO_ZERO \
  if (t < 96){ \
    int pj = t & 3; int side = (t >> 2) & 1; int row = (t >> 3) % 6; int khz = t / 48; \
    lFu[((khz*6 + row)*66 + (side ? 65 : 0))*4 + pj] = 0u; \
  }

// U-kernel: conv of the qv channels (cb 32..63), once per b, raw acc -> U (f32)
__global__ __launch_bounds__(256, 2) void k_convu(const unsigned* __restrict__ fin32,
                                                  const short* __restrict__ Wt2,
                                                  float* __restrict__ U){
  __shared__ __attribute__((aligned(16))) unsigned lFu[2*6*66*4];
  __shared__ __attribute__((aligned(16))) short wbuf[2*9216];
  int blk = blockIdx.x;                  // 512 = 2 h * 2 b * 8 cvb * 16 yb
  int h = blk >> 8, b = (blk >> 7) & 1, cvb = (blk >> 4) & 7, yb = blk & 15;
  int t = threadIdx.x, lane = t & 63, wv = t >> 6;
  int ln = lane & 31, kh = lane >> 5;
  int y0 = yb*4;
  f32x16 accF[2][2] = {}, accA[2][2] = {};
  const unsigned* finB = fin32 + (size_t)(b*4)*2359296;   // n=0 image of this b
  const short* Wslice = Wt2 + (size_t)cvb*72*18432;
  CONV_HALO_ZERO
  CONV_STAGE_DECL
  for (int i = 0; i < 16; i++){
    int cb = 32 + h*16 + i;
    CONV_LOAD_STG(cb)
    __syncthreads();
    CONV_WRITE_STG
    CONV_DMA_W(cb)
    __syncthreads();
    CONV_COMPUTE
  }
  int y = y0 + wv;
  #pragma unroll
  for (int mf = 0; mf < 2; mf++)
  #pragma unroll
  for (int xh = 0; xh < 2; xh++){
    int x = xh*32 + ln;
    #pragma unroll
    for (int reg = 0; reg < 16; reg++){
      int cv = cvb*64 + mf*32 + 4*kh + 8*(reg>>2) + (reg&3);
      size_t o = (size_t)cv*4096 + (size_t)y*64 + x;
      U[((size_t)(h*2 + 0)*2 + b)*2097152 + o] = accF[mf][xh][reg];
      U[((size_t)(h*2 + 1)*2 + b)*2097152 + o] = accA[mf][xh][reg];
    }
  }
}

// main conv: 40 n-dependent cb chunks (mem_out 0..31, S 64..71) + U + bias + gate
__global__ __launch_bounds__(256, 2) void k_conv(const unsigned* __restrict__ fin32,
                                                 const short* __restrict__ Wt2,
                                                 const float* __restrict__ bfv, const float* __restrict__ bav,
                                                 const float* __restrict__ U,
                                                 float* __restrict__ out){
  __shared__ __attribute__((aligned(16))) unsigned lFu[2*6*66*4];
  __shared__ __attribute__((aligned(16))) short wbuf[2*9216];
  int blk = blockIdx.x;                  // 1024 = 8 bn * 8 cvb * 16 yb
  int bn = blk >> 7, cvb = (blk >> 4) & 7, yb = blk & 15;
  int t = threadIdx.x, lane = t & 63, wv = t >> 6;
  int ln = lane & 31, kh = lane >> 5;
  int y0 = yb*4;
  f32x16 accF[2][2] = {}, accA[2][2] = {};
  const unsigned* finB = fin32 + (size_t)bn*2359296;
  const short* Wslice = Wt2 + (size_t)cvb*72*18432;
  CONV_HALO_ZERO
  CONV_STAGE_DECL
  for (int i = 0; i < 40; i++){
    int cb = (i < 32) ? i : i + 32;
    CONV_LOAD_STG(cb)
    __syncthreads();
    CONV_WRITE_STG
    CONV_DMA_W(cb)
    __syncthreads();
    CONV_COMPUTE
  }
  int y = y0 + wv;
  int b = bn >> 2;
  #pragma unroll
  for (int mf = 0; mf < 2; mf++)
  #pragma unroll
  for (int xh = 0; xh < 2; xh++){
    int x = xh*32 + ln;
    #pragma unroll
    for (int reg = 0; reg < 16; reg++){
      int cv = cvb*64 + mf*32 + 4*kh + 8*(reg>>2) + (reg&3);
      size_t o = (size_t)cv*4096 + (size_t)y*64 + x;
      float fv = accF[mf][xh][reg] + bfv[cv]
               + U[((size_t)0*2 + b)*2097152 + o] + U[((size_t)2*2 + b)*2097152 + o];
      float av = accA[mf][xh][reg] + bav[cv]
               + U[((size_t)1*2 + b)*2097152 + o] + U[((size_t)3*2 + b)*2097152 + o];
      out[((size_t)bn*512 + cv)*4096 + (size_t)y*64 + x] = fv/(1.f + __expf(-av));
    }
  }
}

// ---------------- launch ----------------

extern "C" void kernel_launch(void* const* d_in, const int* in_sizes, int n_in,
                              void* d_out, int out_size, void* d_ws, size_t ws_size,
                              hipStream_t stream){
  const float* qk     = (const float*)d_in[0];
  const float* qv     = (const float*)d_in[1];
  const float* qvm    = (const float*)d_in[2];
  const float* masks  = (const float*)d_in[3];
  const float* kappa0 = (const float*)d_in[4];
  const float* nu0    = (const float*)d_in[5];
  const float* zita0  = (const float*)d_in[6];
  const float* Wf     = (const float*)d_in[7];
  const float* bfb    = (const float*)d_in[8];
  const float* Wa     = (const float*)d_in[9];
  const float* bab    = (const float*)d_in[10];
  float* out = (float*)d_out;

  float* ws    = (float*)d_ws;
  float* zzb   = ws;                      // 16,777,216 f  (p_aff later; U after k_mem)
  float* kpart = zzb + 16777216;          // 4,194,304 f
  float* zpart = kpart + 4194304;         // 65,536 f
  float* kn    = zpart + 65536;           // 262,144 f
  float* zita  = kn + 262144;             // 4,096 f
  float* wts   = zita + 4096;             // 65,536 f
  float* xT    = wts + 65536;             // 524,288 f
  float* xTn   = xT + 524288;             // 524,288 f
  short* mv2   = (short*)(xTn + 524288);  // 4,194,304 s
  unsigned* fin32 = (unsigned*)(mv2 + 4194304);  // 18,874,368 u32
  short* Wt2   = (short*)(fin32 + 18874368);     // 10,616,832 s (f/a interleaved per cb)
  float* U     = zzb;                     // 16,777,216 f (aliases zzb; live after k_mem)

  k_prep_x<<<32, 256, 0, stream>>>(qk, xT, xTn);
  k_init_w_kn<<<256, 256, 0, stream>>>(masks, kappa0, wts, kn);
  k_prep_wt2b<<<1152, 256, 0, stream>>>(Wf, Wa, Wt2);
  k_qv_fin<<<32768, 256, 0, stream>>>(qv, fin32);

  for (int it = 0; it < 4; ++it){
    k_zz<<<4096, 256, 0, stream>>>(xT, kn, wts, zzb);
    k_part<<<256, 1024, 0, stream>>>(qk, zzb, kpart, zpart);
    k_fin<<<16, 1024, 0, stream>>>(kpart, zpart, kappa0, zita0, kn, zita);
    if (it < 3) k_sww<<<2048, 512, 0, stream>>>(xTn, kn, masks, wts);
  }

  k_nu<<<256, 256, 0, stream>>>(qvm, zzb, nu0, zita0, zita, mv2);
  k_aff<<<2048, 512, 0, stream>>>(xTn, kn, zzb /* becomes p_aff */);
  k_topk<<<8192, 256, 0, stream>>>(zzb, fin32);
  k_mem<<<1024, 256, 0, stream>>>(mv2, zzb, fin32);
  k_convu<<<512, 256, 0, stream>>>(fin32, Wt2, U);
  k_conv<<<1024, 256, 0, stream>>>(fin32, Wt2, bfb, bab, U, out);
}

// Round 7
// 1958.546 us; speedup vs baseline: 1.1351x; 1.1351x over previous
//
#include <hip/hip_runtime.h>
#include <hip/hip_bf16.h>
#include <math.h>

// Shapes (fixed): B=2 N=4 G=2 Ck=64 Cv=512 H=W=64 HW=4096 L=256 TOPL=64 Cin=1152 BN=8 BNG=16

typedef __attribute__((ext_vector_type(8))) short bf16x8;
typedef __attribute__((ext_vector_type(4))) float f32x4;
typedef __attribute__((ext_vector_type(16))) float f32x16;

static __device__ __forceinline__ short f2b(float f){
  __hip_bfloat16 h = __float2bfloat16(f);
  short s; __builtin_memcpy(&s, &h, 2); return s;
}
static __device__ __forceinline__ unsigned pack2(float lo, float hi){
  return (unsigned)(unsigned short)f2b(lo) | ((unsigned)(unsigned short)f2b(hi) << 16);
}

static __device__ __forceinline__ float wred_max(float v){
  #pragma unroll
  for (int off = 32; off > 0; off >>= 1) v = fmaxf(v, __shfl_xor(v, off));
  return v;
}
static __device__ __forceinline__ float wred_sum(float v){
  #pragma unroll
  for (int off = 32; off > 0; off >>= 1) v += __shfl_xor(v, off);
  return v;
}

// async global->LDS DMA, 16B per lane (dest = uniform base + lane*16)
static __device__ __forceinline__ void gload_lds16(const short* g, short* l){
  __builtin_amdgcn_global_load_lds((const __attribute__((address_space(1))) unsigned int*)(g),
                                   (__attribute__((address_space(3))) unsigned int*)(l),
                                   16, 0, 0);
}

#define FMA16(X0,X1,X2,X3,KV) \
  acc[0]+=X0.x*KV; acc[1]+=X0.y*KV; acc[2]+=X0.z*KV; acc[3]+=X0.w*KV; \
  acc[4]+=X1.x*KV; acc[5]+=X1.y*KV; acc[6]+=X1.z*KV; acc[7]+=X1.w*KV; \
  acc[8]+=X2.x*KV; acc[9]+=X2.y*KV; acc[10]+=X2.z*KV; acc[11]+=X2.w*KV; \
  acc[12]+=X3.x*KV; acc[13]+=X3.y*KV; acc[14]+=X3.z*KV; acc[15]+=X3.w*KV;

// ---------------- prep kernels ----------------

__global__ void k_prep_x(const float* __restrict__ qk, float* __restrict__ xT, float* __restrict__ xTn,
                         float* __restrict__ xnrm){
  int idx = blockIdx.x*256 + threadIdx.x;   // 8192 = B*HW
  int b = idx >> 12, hw = idx & 4095;
  float v[64]; float ss = 0.f;
  #pragma unroll
  for (int k=0;k<64;k++){ v[k] = qk[((size_t)b*64 + k)*4096 + hw]; ss += v[k]*v[k]; }
  float nrm = sqrtf(ss) + 1e-6f;
  float inv = 1.f/nrm;
  xnrm[idx] = nrm;
  #pragma unroll
  for (int k=0;k<64;k++){ xT[(size_t)idx*64 + k] = v[k]; xTn[(size_t)idx*64 + k] = v[k]*inv; }
}

__global__ void k_init_w_kn(const float* __restrict__ masks, const float* __restrict__ kappa0,
                            float* __restrict__ wts, float* __restrict__ kn){
  int t = blockIdx.x*256 + threadIdx.x;   // 65536
  if (t < 16*4096) wts[t] = masks[t];
  if (t < 16*256){
    int bng = t >> 8, l = t & 255;
    float ss = 0.f;
    #pragma unroll 4
    for (int k=0;k<64;k++){ float v = kappa0[((size_t)bng*64 + k)*256 + l]; ss += v*v; }
    float inv = 1.f/(sqrtf(ss) + 1e-6f);
    #pragma unroll 4
    for (int k=0;k<64;k++) kn[((size_t)bng*64 + k)*256 + l] = kappa0[((size_t)bng*64 + k)*256 + l]*inv;
  }
}

// Interleaved weight layout: Wt2[((tile*2 + conv)*9216) + (r*2 + kh)*512 + cvl*8 + j]
__global__ __launch_bounds__(256) void k_prep_wt2b(const float* __restrict__ Wf, const float* __restrict__ Wa,
                                                   short* __restrict__ Wt2){
  __shared__ float wsl[64][145];
  int blk = blockIdx.x;                 // 1152 = 576 tiles * 2 conv
  int conv = blk & 1;
  int tile = blk >> 1;                  // cvb*72 + cb
  int cb = tile % 72;
  int cvb = tile / 72;
  const float* Wsrc = conv ? Wa : Wf;
  int t = threadIdx.x;
  int cvl = t >> 2, part = t & 3;
  const float* src = Wsrc + ((size_t)(cvb*64 + cvl)*1152 + cb*16)*9;
  #pragma unroll
  for (int i = 0; i < 9; i++){
    float4 v = *(const float4*)(src + part*4 + i*16);
    wsl[cvl][part*4 + i*16 + 0] = v.x;
    wsl[cvl][part*4 + i*16 + 1] = v.y;
    wsl[cvl][part*4 + i*16 + 2] = v.z;
    wsl[cvl][part*4 + i*16 + 3] = v.w;
  }
  __syncthreads();
  short* obase = Wt2 + ((size_t)tile*2 + conv)*9216;
  #pragma unroll
  for (int i = 0; i < 5; i++){
    int item = t + i*256;               // [0,1152): (r*2+kh)*64 + cvl2
    if (item < 1152){
      int rk = item >> 6;
      int r = rk >> 1, kh = rk & 1;
      int c2 = item & 63;
      bf16x8 v;
      #pragma unroll
      for (int j = 0; j < 8; j++)
        v[j] = f2b(wsl[c2][(kh*8 + j)*9 + r]);
      *(bf16x8*)(obase + (size_t)item*8) = v;
    }
  }
}

// fin32 pair layout: fin32[bn*576*4096 + p*4096 + hw] = bf16 channels (2p, 2p+1)
__global__ void k_qv_fin(const float* __restrict__ qv, unsigned* __restrict__ fin32){
  int t = blockIdx.x*256 + threadIdx.x;   // 8 * 2^20 threads
  int bn = t >> 20;
  int rem = t & 1048575;
  int p = rem >> 12;
  int hw = rem & 4095;
  int b = bn >> 2;
  float lo = qv[((size_t)b*512 + 2*p)*4096 + hw];
  float hi = qv[((size_t)b*512 + 2*p + 1)*4096 + hw];
  fin32[(size_t)bn*2359296 + (size_t)(256 + p)*4096 + hw] = pack2(lo, hi);
}

// ---------------- EM loop kernels ----------------

__global__ __launch_bounds__(256) void k_zz(const float* __restrict__ xT, const float* __restrict__ kn,
                                            const float* __restrict__ wts, float* __restrict__ zzb){
  int blk = blockIdx.x;                 // 4096 = 16 bng * 256 tiles
  int bng = blk >> 8;
  int hw0 = (blk & 255) * 16;
  int b = bng >> 3;
  int t = threadIdx.x;
  int lane = t & 63, wid = t >> 6;
  __shared__ float xs[64][16];
  __shared__ float redm[4], reds[4];
  {
    int k = t & 63, pq = t >> 6;
    #pragma unroll
    for (int p = pq; p < 16; p += 4)
      xs[k][p] = xT[((size_t)b*4096 + hw0 + p)*64 + k];
  }
  float acc[16];
  #pragma unroll
  for (int p=0;p<16;p++) acc[p] = 0.f;
  __syncthreads();
  const float* knp = kn + (size_t)bng*16384 + t;
  #pragma unroll 2
  for (int k=0;k<64;k++){
    float knv = knp[k*256];
    float4 x0 = *(const float4*)&xs[k][0];
    float4 x1 = *(const float4*)&xs[k][4];
    float4 x2 = *(const float4*)&xs[k][8];
    float4 x3 = *(const float4*)&xs[k][12];
    FMA16(x0,x1,x2,x3,knv)
  }
  #pragma unroll
  for (int p=0;p<16;p++){
    float v = acc[p];
    float m = wred_max(v);
    if (lane==0) redm[wid] = m;
    __syncthreads();
    m = fmaxf(fmaxf(redm[0],redm[1]), fmaxf(redm[2],redm[3]));
    float e = __expf((v - m) * 20.0f);
    float s = wred_sum(e);
    if (lane==0) reds[wid] = s;
    __syncthreads();
    s = reds[0]+reds[1]+reds[2]+reds[3];
    float wgt = wts[bng*4096 + hw0 + p];
    zzb[((size_t)bng*4096 + hw0 + p)*256 + t] = e/s*wgt;
  }
}

// v7: fused sww + next-iteration zz. Both need the SAME GEMM s = xn^T . kn
// (k_sww(it) and k_zz(it+1) use the identical kn); z = s * xnrm recovers the
// unnormalized logits exactly (xnrm = sqrt(ss)+1e-6 is the exact inverse of
// the xn normalization). One GEMM, two epilogues: new weights (sww) feed the
// zz softmax directly — the wts round-trip through memory disappears too.
__global__ __launch_bounds__(512) void k_swz(const float* __restrict__ xTn, const float* __restrict__ kn,
                                             const float* __restrict__ masks, const float* __restrict__ xnrm,
                                             float* __restrict__ zzb){
  int blk = blockIdx.x;                 // 2048 = 8 bn * 256 tiles
  int bnI = blk >> 8;
  int hw0 = (blk & 255)*16;
  int b = bnI >> 2;
  int t = threadIdx.x;
  int lane = t & 63, wid = t >> 6;
  int g = t >> 8; int l = t & 255;
  int bng = bnI*2 + g;
  __shared__ float xs[64][16];
  __shared__ float xnr[16];
  __shared__ float redm[8], reds[8], redz[8];
  {
    int k = t & 63, pq = t >> 6;
    #pragma unroll
    for (int p = pq; p < 16; p += 8)
      xs[k][p] = xTn[((size_t)b*4096 + hw0 + p)*64 + k];
  }
  if (t < 16) xnr[t] = xnrm[b*4096 + hw0 + t];
  float knr[64];
  const float* knp = kn + (size_t)bng*16384 + l;
  #pragma unroll
  for (int k=0;k<64;k++) knr[k] = knp[k*256];
  float acc[16];
  #pragma unroll
  for (int p=0;p<16;p++) acc[p]=0.f;
  __syncthreads();
  #pragma unroll 2
  for (int k=0;k<64;k++){
    float knv = knr[k];
    float4 x0 = *(const float4*)&xs[k][0];
    float4 x1 = *(const float4*)&xs[k][4];
    float4 x2 = *(const float4*)&xs[k][8];
    float4 x3 = *(const float4*)&xs[k][12];
    FMA16(x0,x1,x2,x3,knv)
  }
  #pragma unroll
  for (int p=0;p<16;p++){
    float v = acc[p];
    float m = wred_max(v);
    if (lane==0) redm[wid] = m;
    __syncthreads();
    float mg0 = fmaxf(fmaxf(redm[0],redm[1]), fmaxf(redm[2],redm[3]));
    float mg1 = fmaxf(fmaxf(redm[4],redm[5]), fmaxf(redm[6],redm[7]));
    float mall = fmaxf(mg0, mg1);
    float mg = g ? mg1 : mg0;
    float nf = xnr[p];
    float es = __expf((v - mall) * 20.0f);          // sww: shared max over both g
    float ez = __expf((v - mg) * 20.0f * nf);       // zz: per-g max, logits z = v*nf
    float ssum = wred_sum(es);
    float zsum = wred_sum(ez);
    if (lane==0){ reds[wid] = ssum; redz[wid] = zsum; }
    __syncthreads();
    float s0 = reds[0]+reds[1]+reds[2]+reds[3];
    float s1 = reds[4]+reds[5]+reds[6]+reds[7];
    float szg = g ? (redz[4]+redz[5]+redz[6]+redz[7])
                  : (redz[0]+redz[1]+redz[2]+redz[3]);
    float sg = g ? s1 : s0;
    float wgt = masks[bng*4096 + hw0 + p]*(1.f - sg/(s0+s1));
    zzb[((size_t)bng*4096 + hw0 + p)*256 + l] = ez/szg*wgt;
  }
}

// v6: zz chunk staged in LDS once (each element read once from global)
__global__ __launch_bounds__(1024) void k_part(const float* __restrict__ qk, const float* __restrict__ zzb,
                                               float* __restrict__ kpart, float* __restrict__ zpart){
  int bng = blockIdx.x >> 4, ch = blockIdx.x & 15;   // 256 blocks
  int b = bng >> 3;
  int t = threadIdx.x; int l = t & 255; int kq = t >> 8;
  __shared__ float xs[64][80];
  __shared__ float zlds[16][256];
  float acc[16];
  #pragma unroll
  for (int j=0;j<16;j++) acc[j]=0.f;
  float zs = 0.f;
  for (int sc=0; sc<4; sc++){
    int hwb = ch*256 + sc*64;
    __syncthreads();
    {
      int hw_l = t & 63, kk = t >> 6;
      #pragma unroll
      for (int k = kk; k < 64; k += 16)
        xs[hw_l][k] = qk[((size_t)b*64 + k)*4096 + hwb + hw_l];
    }
    for (int chunk=0; chunk<4; chunk++){
      #pragma unroll
      for (int i=0;i<4;i++){
        int e = t + i*1024;
        int hh = e >> 8, l2 = e & 255;
        zlds[hh][l2] = zzb[((size_t)bng*4096 + hwb + chunk*16 + hh)*256 + l2];
      }
      __syncthreads();
      #pragma unroll 2
      for (int hh=0; hh<16; hh++){
        int hw_l = chunk*16 + hh;
        float zv = zlds[hh][l];
        zs += zv;
        const float* xp = &xs[hw_l][kq*16];
        float4 x0 = *(const float4*)(xp);
        float4 x1 = *(const float4*)(xp+4);
        float4 x2 = *(const float4*)(xp+8);
        float4 x3 = *(const float4*)(xp+12);
        FMA16(x0,x1,x2,x3,zv)
      }
      __syncthreads();
    }
  }
  #pragma unroll
  for (int j=0;j<16;j++)
    kpart[(((size_t)bng*16 + ch)*64 + kq*16 + j)*256 + l] = acc[j];
  if (kq == 0) zpart[((size_t)bng*16 + ch)*256 + l] = zs;
}

// v7: grid 16 -> 64 blocks (bng x 4 l-chunks) — the old 16-block grid used 6%
// of CUs for a 16MB reduction; 4x the memory parallelism.
__global__ __launch_bounds__(1024) void k_fin(const float* __restrict__ kpart, const float* __restrict__ zpart,
                                              const float* __restrict__ kappa0, const float* __restrict__ zita0,
                                              float* __restrict__ kn, float* __restrict__ zita){
  int bng = blockIdx.x >> 2, lq = blockIdx.x & 3;  // 64 blocks
  int t = threadIdx.x;
  int ll = t & 63, kq = t >> 6;                    // 16 kq x 4 k
  int l = lq*64 + ll;
  __shared__ float invs[64];
  __shared__ float ssr[16][64];
  __shared__ float ninvs[64];
  float z0 = zita0[bng*256 + l];
  if (kq == 0){
    float zs = z0;
    #pragma unroll
    for (int ch=0; ch<16; ch++) zs += zpart[((size_t)bng*16 + ch)*256 + l];
    zita[bng*256 + l] = zs;
    invs[ll] = 1.f/zs;
  }
  __syncthreads();
  float inv = invs[ll];
  float kap[4]; float ss = 0.f;
  #pragma unroll
  for (int j=0;j<4;j++){
    int k = kq*4 + j;
    float a = z0 * kappa0[((size_t)bng*64 + k)*256 + l];
    #pragma unroll
    for (int ch=0; ch<16; ch++) a += kpart[(((size_t)bng*16 + ch)*64 + k)*256 + l];
    float kv = a*inv; kap[j] = kv; ss += kv*kv;
  }
  ssr[kq][ll] = ss;
  __syncthreads();
  if (kq == 0){
    float tot = 0.f;
    #pragma unroll
    for (int q=0;q<16;q++) tot += ssr[q][ll];
    ninvs[ll] = 1.f/(sqrtf(tot) + 1e-6f);
  }
  __syncthreads();
  float ninv = ninvs[ll];
  #pragma unroll
  for (int j=0;j<4;j++) kn[((size_t)bng*64 + kq*4 + j)*256 + l] = kap[j]*ninv;
}

__global__ __launch_bounds__(512) void k_aff(const float* __restrict__ xTn, const float* __restrict__ kn,
                                             float* __restrict__ paff){
  int blk = blockIdx.x;                 // 2048
  int bnI = blk >> 8;
  int hw0 = (blk & 255)*16;
  int b = bnI >> 2;
  int t = threadIdx.x;
  int lane = t & 63, wid = t >> 6;
  int g = t >> 8; int l = t & 255;
  int bng = bnI*2 + g;
  __shared__ float xs[64][16];
  __shared__ float redm[8], reds[8];
  {
    int k = t & 63, pq = t >> 6;
    #pragma unroll
    for (int p = pq; p < 16; p += 8)
      xs[k][p] = xTn[((size_t)b*4096 + hw0 + p)*64 + k];
  }
  float knr[64];
  const float* knp = kn + (size_t)bng*16384 + l;
  #pragma unroll
  for (int k=0;k<64;k++) knr[k] = knp[k*256];
  float acc[16];
  #pragma unroll
  for (int p=0;p<16;p++) acc[p]=0.f;
  __syncthreads();
  #pragma unroll 2
  for (int k=0;k<64;k++){
    float knv = knr[k];
    float4 x0 = *(const float4*)&xs[k][0];
    float4 x1 = *(const float4*)&xs[k][4];
    float4 x2 = *(const float4*)&xs[k][8];
    float4 x3 = *(const float4*)&xs[k][12];
    FMA16(x0,x1,x2,x3,knv)
  }
  #pragma unroll
  for (int p=0;p<16;p++){
    float v = acc[p];
    float m = wred_max(v);
    if (lane==0) redm[wid] = m;
    __syncthreads();
    m = fmaxf(fmaxf(fmaxf(redm[0],redm[1]),fmaxf(redm[2],redm[3])),
              fmaxf(fmaxf(redm[4],redm[5]),fmaxf(redm[6],redm[7])));
    float e = __expf((v - m) * 20.0f);
    float s = wred_sum(e);
    if (lane==0) reds[wid] = s;
    __syncthreads();
    float tot = reds[0]+reds[1]+reds[2]+reds[3]+reds[4]+reds[5]+reds[6]+reds[7];
    paff[((size_t)bnI*4096 + hw0 + p)*512 + t] = e/tot;
  }
}

// ---------------- top-k / S channels ----------------

static __device__ __forceinline__ float topk_cum(float va, float vb, float vc, float vd, int lane){
  float run = 0.f, cme = 0.f;
  #pragma unroll 2
  for (int tt=0; tt<64; tt++){
    float m = fmaxf(fmaxf(va,vb), fmaxf(vc,vd));
    float wm = wred_max(m);
    run += wm;
    if (lane == tt) cme = run;
    unsigned long long ball = __ballot(m == wm);
    int wl = __ffsll(ball) - 1;
    if (lane == wl){
      if (va == wm) va = -1.f;
      else if (vb == wm) vb = -1.f;
      else if (vc == wm) vc = -1.f;
      else vd = -1.f;
    }
  }
  return cme;
}

__global__ __launch_bounds__(256) void k_topk(const float* __restrict__ paff, unsigned* __restrict__ fin32){
  int wid = threadIdx.x >> 6, lane = threadIdx.x & 63;
  int px = blockIdx.x*4 + wid;           // 32768 pixels
  int bn = px >> 12, hw = px & 4095;
  const float* row = paff + (size_t)px*512;
  float4 a0 = *(const float4*)(row + lane*4);
  float4 a1 = *(const float4*)(row + 256 + lane*4);
  float c0 = topk_cum(a0.x,a0.y,a0.z,a0.w, lane);
  float c1 = topk_cum(a1.x,a1.y,a1.z,a1.w, lane);
  float sf = c0/(c0+c1);
  float sf2 = __shfl_down(sf, 1);
  if (!(lane & 1)){
    size_t base = (size_t)bn*2359296;
    fin32[base + (size_t)(512 + (lane>>1))*4096 + hw] = pack2(sf, sf2);
    fin32[base + (size_t)(544 + (lane>>1))*4096 + hw] = pack2(1.f - sf, 1.f - sf2);
  }
}

// ---------------- MFMA GEMMs ----------------

// nu: C[cv][l] = qv_mem[bn] (Cv x HW) . zz[bng] (HW x L); epilogue -> mv2 bf16
__global__ __launch_bounds__(256) void k_nu(const float* __restrict__ qvm, const float* __restrict__ zzb,
                                            const float* __restrict__ nu0, const float* __restrict__ zita0,
                                            const float* __restrict__ zita, short* __restrict__ mv2){
  constexpr int AP = 40;
  __shared__ short lA[64*AP];
  __shared__ short lB[128*AP];
  int blk = blockIdx.x;                  // 256 = 16 bng * 8 cvb * 2 lb
  int bng = blk >> 4, cvb = (blk >> 1) & 7, lb = blk & 1;
  int bn = bng >> 1, g = bng & 1;
  int t = threadIdx.x, lane = t & 63, w = t >> 6;
  int wm = w >> 1, wn = w & 1;
  int quad = lane >> 4, fr = lane & 15;
  f32x4 acc[2][4] = {};
  const float* Ab = qvm + ((size_t)bn*512 + cvb*64)*4096;
  const float* Bb = zzb + (size_t)bng*4096*256 + lb*128;
  int arow = t >> 2, acg = (t & 3)*8;
  int bhw = t & 31, blg = (t >> 5)*8;
  for (int k0 = 0; k0 < 4096; k0 += 32){
    __syncthreads();
    {
      const float* s = Ab + (size_t)arow*4096 + k0 + acg;
      float4 f0 = *(const float4*)s, f1 = *(const float4*)(s+4);
      bf16x8 v;
      v[0]=f2b(f0.x); v[1]=f2b(f0.y); v[2]=f2b(f0.z); v[3]=f2b(f0.w);
      v[4]=f2b(f1.x); v[5]=f2b(f1.y); v[6]=f2b(f1.z); v[7]=f2b(f1.w);
      *(bf16x8*)&lA[arow*AP + acg] = v;
    }
    #pragma unroll
    for (int h = 0; h < 2; h++){
      int l0 = h*64 + blg;
      const float* s = Bb + (size_t)(k0 + bhw)*256 + l0;
      float4 f0 = *(const float4*)s, f1 = *(const float4*)(s+4);
      lB[(l0+0)*AP + bhw] = f2b(f0.x);
      lB[(l0+1)*AP + bhw] = f2b(f0.y);
      lB[(l0+2)*AP + bhw] = f2b(f0.z);
      lB[(l0+3)*AP + bhw] = f2b(f0.w);
      lB[(l0+4)*AP + bhw] = f2b(f1.x);
      lB[(l0+5)*AP + bhw] = f2b(f1.y);
      lB[(l0+6)*AP + bhw] = f2b(f1.z);
      lB[(l0+7)*AP + bhw] = f2b(f1.w);
    }
    __syncthreads();
    int koff = quad*8;
    bf16x8 a0 = *(const bf16x8*)&lA[(wm*32 +  0 + fr)*AP + koff];
    bf16x8 a1 = *(const bf16x8*)&lA[(wm*32 + 16 + fr)*AP + koff];
    #pragma unroll
    for (int nf=0; nf<4; nf++){
      bf16x8 bv = *(const bf16x8*)&lB[(wn*64 + nf*16 + fr)*AP + koff];
      acc[0][nf] = __builtin_amdgcn_mfma_f32_16x16x32_bf16(a0,bv,acc[0][nf],0,0,0);
      acc[1][nf] = __builtin_amdgcn_mfma_f32_16x16x32_bf16(a1,bv,acc[1][nf],0,0,0);
    }
  }
  #pragma unroll
  for (int mf=0; mf<2; mf++)
  #pragma unroll
  for (int nf=0; nf<4; nf++)
  #pragma unroll
  for (int r=0;r<4;r++){
    int cv = cvb*64 + wm*32 + mf*16 + quad*4 + r;
    int l  = lb*128 + wn*64 + nf*16 + fr;
    float c = acc[mf][nf][r];
    float z0 = zita0[bng*256 + l];
    float nv = (z0 * nu0[((size_t)bng*512 + cv)*256 + l] + c) / zita[bng*256 + l];
    mv2[((size_t)bn*512 + cv)*512 + g*256 + l] = f2b(nv);
  }
}

// mem_out: C[cv][hw] = mv2[bn] (Cv x 2L) . p_aff[bn] (2L x HW) -> fin32 pairs [0,256)
__global__ __launch_bounds__(256) void k_mem(const short* __restrict__ mv2, const float* __restrict__ paff,
                                             unsigned* __restrict__ fin32){
  constexpr int BP = 40;
  __shared__ short lB[256*BP];
  int blk = blockIdx.x;                  // 1024 = 8 bn * 8 cvb * 16 hwb
  int bn = blk >> 7, cvb = (blk >> 4) & 7, hwb = blk & 15;
  int t = threadIdx.x, lane = t & 63, w = t >> 6;
  int quad = lane >> 4, fr = lane & 15;
  f32x4 acc[4][4] = {};
  const short* Ab = mv2 + ((size_t)bn*512 + cvb*64)*512;
  const float* Bb = paff + ((size_t)bn*4096 + hwb*256)*512;
  for (int k0=0; k0<512; k0+=32){
    __syncthreads();
    {
      const float* s = Bb + (size_t)t*512 + k0;
      #pragma unroll
      for (int q=0;q<4;q++){
        float4 f0 = *(const float4*)(s + q*8);
        float4 f1 = *(const float4*)(s + q*8 + 4);
        bf16x8 v;
        v[0]=f2b(f0.x); v[1]=f2b(f0.y); v[2]=f2b(f0.z); v[3]=f2b(f0.w);
        v[4]=f2b(f1.x); v[5]=f2b(f1.y); v[6]=f2b(f1.z); v[7]=f2b(f1.w);
        *(bf16x8*)&lB[t*BP + q*8] = v;
      }
    }
    __syncthreads();
    int koff = quad*8;
    bf16x8 af[4];
    #pragma unroll
    for (int mf=0; mf<4; mf++)
      af[mf] = *(const bf16x8*)(Ab + (size_t)(mf*16 + fr)*512 + k0 + koff);
    #pragma unroll
    for (int nf=0; nf<4; nf++){
      bf16x8 bv = *(const bf16x8*)&lB[(w*64 + nf*16 + fr)*BP + koff];
      #pragma unroll
      for (int mf=0; mf<4; mf++)
        acc[mf][nf] = __builtin_amdgcn_mfma_f32_16x16x32_bf16(af[mf], bv, acc[mf][nf],0,0,0);
    }
  }
  #pragma unroll
  for (int mf=0;mf<4;mf++)
  #pragma unroll
  for (int nf=0;nf<4;nf++){
    int hw = hwb*256 + w*64 + nf*16 + fr;
    int p0 = cvb*32 + mf*8 + quad*2;     // pair index of (cv0,cv1)
    unsigned lo = pack2(acc[mf][nf][0], acc[mf][nf][1]);
    unsigned hi = pack2(acc[mf][nf][2], acc[mf][nf][3]);
    fin32[(size_t)bn*2359296 + (size_t)p0*4096 + hw] = lo;
    fin32[(size_t)bn*2359296 + (size_t)(p0+1)*4096 + hw] = hi;
  }
}

// ---- shared conv body macros (v3 structure) + qv-fold (U precompute) ----

#define CONV_STAGE_DECL \
  unsigned stg[3][4];
#define CONV_LOAD_STG(CB) { \
    _Pragma("unroll") \
    for (int i = 0; i < 3; i++){ \
      int tk = wv*3 + i; \
      int skh = (tk >= 6) ? 1 : 0; \
      int srow = tk - skh*6; \
      int gy = y0 - 1 + srow; \
      bool ok = (gy >= 0 && gy < 64); \
      _Pragma("unroll") \
      for (int pj = 0; pj < 4; pj++) \
        stg[i][pj] = ok ? finB[(size_t)((CB)*8 + skh*4 + pj)*4096 + gy*64 + lane] : 0u; \
    } }
#define CONV_WRITE_STG { \
    _Pragma("unroll") \
    for (int i = 0; i < 3; i++){ \
      int tk = wv*3 + i; \
      int skh = (tk >= 6) ? 1 : 0; \
      int srow = tk - skh*6; \
      uint4 v; v.x = stg[i][0]; v.y = stg[i][1]; v.z = stg[i][2]; v.w = stg[i][3]; \
      *(uint4*)&lFu[((skh*6 + srow)*66 + lane + 1)*4] = v; \
    } }
#define CONV_DMA_W(CB) { \
    const short* src = Wslice + (size_t)(CB)*18432 + lane*8; \
    _Pragma("unroll") \
    for (int i = 0; i < 9; i++){ \
      int idx = wv*9 + i; \
      gload_lds16(src + idx*512, &wbuf[idx*512]); \
    } }
#define CONV_COMPUTE { \
    __builtin_amdgcn_s_setprio(1); \
    _Pragma("unroll 3") \
    for (int r9 = 0; r9 < 9; r9++){ \
      int dy = r9/3, dx = r9 - dy*3; \
      bf16x8 f0 = *(const bf16x8*)(wbuf + r9*1024 + kh*512 + ln*8); \
      bf16x8 f1 = *(const bf16x8*)(wbuf + r9*1024 + kh*512 + ln*8 + 256); \
      bf16x8 a0 = *(const bf16x8*)(wbuf + 9216 + r9*1024 + kh*512 + ln*8); \
      bf16x8 a1 = *(const bf16x8*)(wbuf + 9216 + r9*1024 + kh*512 + ln*8 + 256); \
      int row = wv + dy; \
      _Pragma("unroll") \
      for (int xh = 0; xh < 2; xh++){ \
        bf16x8 bv = *(const bf16x8*)((const short*)lFu + (((kh*6 + row)*66 + xh*32 + ln + dx)*8)); \
        accF[0][xh] = __builtin_amdgcn_mfma_f32_32x32x16_bf16(f0, bv, accF[0][xh],0,0,0); \
        accF[1][xh] = __builtin_amdgcn_mfma_f32_32x32x16_bf16(f1, bv, accF[1][xh],0,0,0); \
        accA[0][xh] = __builtin_amdgcn_mfma_f32_32x32x16_bf16(a0, bv, accA[0][xh],0,0,0); \
        accA[1][xh] = __builtin_amdgcn_mfma_f32_32x32x16_bf16(a1, bv, accA[1][xh],0,0,0); \
      } \
    } \
    __builtin_amdgcn_s_setprio(0); }
#define CONV_HALO_ZERO \
  if (t < 96){ \
    int pj = t & 3; int side = (t >> 2) & 1; int row = (t >> 3) % 6; int khz = t / 48; \
    lFu[((khz*6 + row)*66 + (side ? 65 : 0))*4 + pj] = 0u; \
  }

// U-kernel: conv of the qv channels (cb 32..63), once per b, raw acc -> U (f32)
__global__ __launch_bounds__(256, 2) void k_convu(const unsigned* __restrict__ fin32,
                                                  const short* __restrict__ Wt2,
                                                  float* __restrict__ U){
  __shared__ __attribute__((aligned(16))) unsigned lFu[2*6*66*4];
  __shared__ __attribute__((aligned(16))) short wbuf[2*9216];
  int blk = blockIdx.x;                  // 512 = 2 h * 2 b * 8 cvb * 16 yb
  int h = blk >> 8, b = (blk >> 7) & 1, cvb = (blk >> 4) & 7, yb = blk & 15;
  int t = threadIdx.x, lane = t & 63, wv = t >> 6;
  int ln = lane & 31, kh = lane >> 5;
  int y0 = yb*4;
  f32x16 accF[2][2] = {}, accA[2][2] = {};
  const unsigned* finB = fin32 + (size_t)(b*4)*2359296;   // n=0 image of this b
  const short* Wslice = Wt2 + (size_t)cvb*72*18432;
  CONV_HALO_ZERO
  CONV_STAGE_DECL
  for (int i = 0; i < 16; i++){
    int cb = 32 + h*16 + i;
    CONV_LOAD_STG(cb)
    __syncthreads();
    CONV_WRITE_STG
    CONV_DMA_W(cb)
    __syncthreads();
    CONV_COMPUTE
  }
  int y = y0 + wv;
  #pragma unroll
  for (int mf = 0; mf < 2; mf++)
  #pragma unroll
  for (int xh = 0; xh < 2; xh++){
    int x = xh*32 + ln;
    #pragma unroll
    for (int reg = 0; reg < 16; reg++){
      int cv = cvb*64 + mf*32 + 4*kh + 8*(reg>>2) + (reg&3);
      size_t o = (size_t)cv*4096 + (size_t)y*64 + x;
      U[((size_t)(h*2 + 0)*2 + b)*2097152 + o] = accF[mf][xh][reg];
      U[((size_t)(h*2 + 1)*2 + b)*2097152 + o] = accA[mf][xh][reg];
    }
  }
}

// main conv: 40 n-dependent cb chunks (mem_out 0..31, S 64..71) + U + bias + gate
__global__ __launch_bounds__(256, 2) void k_conv(const unsigned* __restrict__ fin32,
                                                 const short* __restrict__ Wt2,
                                                 const float* __restrict__ bfv, const float* __restrict__ bav,
                                                 const float* __restrict__ U,
                                                 float* __restrict__ out){
  __shared__ __attribute__((aligned(16))) unsigned lFu[2*6*66*4];
  __shared__ __attribute__((aligned(16))) short wbuf[2*9216];
  int blk = blockIdx.x;                  // 1024 = 8 bn * 8 cvb * 16 yb
  int bn = blk >> 7, cvb = (blk >> 4) & 7, yb = blk & 15;
  int t = threadIdx.x, lane = t & 63, wv = t >> 6;
  int ln = lane & 31, kh = lane >> 5;
  int y0 = yb*4;
  f32x16 accF[2][2] = {}, accA[2][2] = {};
  const unsigned* finB = fin32 + (size_t)bn*2359296;
  const short* Wslice = Wt2 + (size_t)cvb*72*18432;
  CONV_HALO_ZERO
  CONV_STAGE_DECL
  for (int i = 0; i < 40; i++){
    int cb = (i < 32) ? i : i + 32;
    CONV_LOAD_STG(cb)
    __syncthreads();
    CONV_WRITE_STG
    CONV_DMA_W(cb)
    __syncthreads();
    CONV_COMPUTE
  }
  int y = y0 + wv;
  int b = bn >> 2;
  #pragma unroll
  for (int mf = 0; mf < 2; mf++)
  #pragma unroll
  for (int xh = 0; xh < 2; xh++){
    int x = xh*32 + ln;
    #pragma unroll
    for (int reg = 0; reg < 16; reg++){
      int cv = cvb*64 + mf*32 + 4*kh + 8*(reg>>2) + (reg&3);
      size_t o = (size_t)cv*4096 + (size_t)y*64 + x;
      float fv = accF[mf][xh][reg] + bfv[cv]
               + U[((size_t)0*2 + b)*2097152 + o] + U[((size_t)2*2 + b)*2097152 + o];
      float av = accA[mf][xh][reg] + bav[cv]
               + U[((size_t)1*2 + b)*2097152 + o] + U[((size_t)3*2 + b)*2097152 + o];
      out[((size_t)bn*512 + cv)*4096 + (size_t)y*64 + x] = fv/(1.f + __expf(-av));
    }
  }
}

// ---------------- launch ----------------

extern "C" void kernel_launch(void* const* d_in, const int* in_sizes, int n_in,
                              void* d_out, int out_size, void* d_ws, size_t ws_size,
                              hipStream_t stream){
  const float* qk     = (const float*)d_in[0];
  const float* qv     = (const float*)d_in[1];
  const float* qvm    = (const float*)d_in[2];
  const float* masks  = (const float*)d_in[3];
  const float* kappa0 = (const float*)d_in[4];
  const float* nu0    = (const float*)d_in[5];
  const float* zita0  = (const float*)d_in[6];
  const float* Wf     = (const float*)d_in[7];
  const float* bfb    = (const float*)d_in[8];
  const float* Wa     = (const float*)d_in[9];
  const float* bab    = (const float*)d_in[10];
  float* out = (float*)d_out;

  float* ws    = (float*)d_ws;
  float* zzb   = ws;                      // 16,777,216 f  (p_aff later; U after k_mem)
  float* kpart = zzb + 16777216;          // 4,194,304 f
  float* zpart = kpart + 4194304;         // 65,536 f
  float* kn    = zpart + 65536;           // 262,144 f
  float* zita  = kn + 262144;             // 4,096 f
  float* wts   = zita + 4096;             // 65,536 f
  float* xT    = wts + 65536;             // 524,288 f
  float* xTn   = xT + 524288;             // 524,288 f
  float* xnrm  = xTn + 524288;            // 8,192 f
  short* mv2   = (short*)(xnrm + 8192);   // 4,194,304 s
  unsigned* fin32 = (unsigned*)(mv2 + 4194304);  // 18,874,368 u32
  short* Wt2   = (short*)(fin32 + 18874368);     // 10,616,832 s (f/a interleaved per cb)
  float* U     = zzb;                     // 16,777,216 f (aliases zzb; live after k_mem)

  k_prep_x<<<32, 256, 0, stream>>>(qk, xT, xTn, xnrm);
  k_init_w_kn<<<256, 256, 0, stream>>>(masks, kappa0, wts, kn);
  k_prep_wt2b<<<1152, 256, 0, stream>>>(Wf, Wa, Wt2);
  k_qv_fin<<<32768, 256, 0, stream>>>(qv, fin32);

  k_zz<<<4096, 256, 0, stream>>>(xT, kn, wts, zzb);      // it0 (weights = masks)
  for (int it = 0; it < 4; ++it){
    k_part<<<256, 1024, 0, stream>>>(qk, zzb, kpart, zpart);
    k_fin<<<64, 1024, 0, stream>>>(kpart, zpart, kappa0, zita0, kn, zita);
    if (it < 3) k_swz<<<2048, 512, 0, stream>>>(xTn, kn, masks, xnrm, zzb);
  }

  k_nu<<<256, 256, 0, stream>>>(qvm, zzb, nu0, zita0, zita, mv2);
  k_aff<<<2048, 512, 0, stream>>>(xTn, kn, zzb /* becomes p_aff */);
  k_topk<<<8192, 256, 0, stream>>>(zzb, fin32);
  k_mem<<<1024, 256, 0, stream>>>(mv2, zzb, fin32);
  k_convu<<<512, 256, 0, stream>>>(fin32, Wt2, U);
  k_conv<<<1024, 256, 0, stream>>>(fin32, Wt2, bfb, bab, U, out);
}